// Round 5
// baseline (817.785 us; speedup 1.0000x reference)
//
#include <hip/hip_runtime.h>
#include <math.h>

#define NB 8192     // batch rows
#define DD 512      // hidden dim
#define KC 4096     // codebook size
#define NL 4        // layers

#define NTB 32      // part[] column tiles (128 codes each)
#define MARGIN 4.0f // bf16-dot candidate margin (>> 2*max bf16 dot error ~0.3)

// GEMM geometry: 256x256 tile, BK=32, 16 K-tiles, 8 waves (2M x 4N)
#define GBM 256
#define GBN 256

typedef __bf16 bf16x8 __attribute__((ext_vector_type(8)));
typedef float  f32x4  __attribute__((ext_vector_type(4)));
typedef unsigned short u16;

struct Top2 { float v1; int i1; float v2; int i2; };

__device__ __forceinline__ u16 f2bf(float f) {   // RNE fp32 -> bf16
    unsigned u = __float_as_uint(f);
    return (u16)((u + 0x7fffu + ((u >> 16) & 1u)) >> 16);
}

__device__ __forceinline__ void top2_insert(float v, int idx, float& v1, int& i1, float& v2, int& i2) {
    if (v > v1 || (v == v1 && idx < i1)) { v2 = v1; i2 = i1; v1 = v; i1 = idx; }
    else if (v > v2 || (v == v2 && idx < i2)) { v2 = v; i2 = idx; }
}

__device__ __forceinline__ void pick_better(float av, int ai, float bv, int bi, float& ov, int& oi) {
    if (av > bv || (av == bv && ai < bi)) { ov = av; oi = ai; } else { ov = bv; oi = bi; }
}

// fp32 -> bf16 bulk convert (n4 = count/4)
__global__ __launch_bounds__(256)
void k_cvt_bf16(const float* __restrict__ src, u16* __restrict__ dst, int n4)
{
    const int i = blockIdx.x * 256 + threadIdx.x;
    if (i < n4) {
        const float4 f = ((const float4*)src)[i];
        uint2 p;
        p.x = (unsigned)f2bf(f.x) | ((unsigned)f2bf(f.y) << 16);
        p.y = (unsigned)f2bf(f.z) | ((unsigned)f2bf(f.w) << 16);
        ((uint2*)dst)[i] = p;
    }
}

// bf16 MFMA GEMM sim = Rb [NB x DD] @ Cb^T [KC x DD], 256x256 tile, BK=32,
// REGISTER-staged (T14): plain global_load_dwordx4 issued 2 K-tiles ahead into
// named ping-pong regs, ds_write_b128 publish + single raw s_barrier per tile
// (lgkmcnt(0) only -- vmcnt handled by compiler scoreboard; prefetch queue is
// never drained). Both-side XOR swizzle chunk^=(r&3)^((r>>2)&3): write and
// read patterns verified 8-lanes-per-4-bank-group (conflict-free).
// Fused per-row top-2 per 128-code half -> part[NB][32].
__global__ __launch_bounds__(512, 2)
void k_simtop2(const u16* __restrict__ Rb, const u16* __restrict__ Cb,
               Top2* __restrict__ part /* [NB][NTB] */)
{
    __shared__ __align__(16) u16 As[2][8192];   // [buf][256 rows x 32 k] = 32 KB
    __shared__ __align__(16) u16 Bs[2][8192];   // 32 KB

    const int tid  = threadIdx.x;
    const int lane = tid & 63;
    const int w    = tid >> 6;        // 0..7
    const int wm   = w >> 2;          // 0..1  (row half)
    const int wn   = w & 3;           // 0..3  (col quarter)

    // XCD chunking: 512 blocks -> 8 chunks of 8x8 tiles (A 2MB + B 2MB ~ L2)
    const int bid = blockIdx.x;
    const int xcd = bid & 7;
    const int idx = bid >> 3;                           // 0..63
    const int row_pan  = (xcd >> 1) * 8 + (idx >> 3);   // 0..31
    const int col_tile = (xcd & 1) * 8 + (idx & 7);     // 0..15
    const int rb0 = row_pan * GBM;
    const int cb0 = col_tile * GBN;

    // staging: thread covers row r = tid>>1, k-chunk pair {2h, 2h+1}, h = tid&1.
    // global chunk c stored at LDS chunk c ^ f(r), f(r) = (r&3)^((r>>2)&3).
    const int rowA = tid >> 1;
    const int h    = tid & 1;
    const int fr   = (rowA & 3) ^ ((rowA >> 2) & 3);
    const char* gAb = (const char*)Rb + (size_t)(rb0 + rowA) * 1024 + h * 32;
    const char* gBb = (const char*)Cb + (size_t)(cb0 + rowA) * 1024 + h * 32;
    const int wpos0 = rowA * 64 + (((2 * h)     ^ fr) << 4);
    const int wpos1 = rowA * 64 + (((2 * h + 1) ^ fr) << 4);

    // fragment reads: row = wsub + m*16 + la, chunk = ks ^ f(la)
    const int la = lane & 15, ks = lane >> 4;
    const int fla = (la & 3) ^ ((la >> 2) & 3);
    const int offA = (wm * 128 + la) * 64 + ((ks ^ fla) << 4);
    const int offB = (wn * 64  + la) * 64 + ((ks ^ fla) << 4);

    f32x4 acc[8][4];
    const f32x4 zero = {0.f, 0.f, 0.f, 0.f};
#pragma unroll
    for (int m = 0; m < 8; ++m)
#pragma unroll
        for (int n = 0; n < 4; ++n) acc[m][n] = zero;

    uint4 eA0, eA1, eB0, eB1;   // even-tile staging regs
    uint4 oA0, oA1, oB0, oB1;   // odd-tile staging regs

#define LOADT(rA0, rA1, rB0, rB1, T) do {                    \
        const char* _pa = gAb + (T) * 64;                    \
        rA0 = *(const uint4*)(_pa);                          \
        rA1 = *(const uint4*)(_pa + 16);                     \
        const char* _pb = gBb + (T) * 64;                    \
        rB0 = *(const uint4*)(_pb);                          \
        rB1 = *(const uint4*)(_pb + 16);                     \
    } while (0)

#define ITER(T, rA0, rA1, rB0, rB1, P) do {                               \
        *(uint4*)((char*)&As[P][0] + wpos0) = rA0;                        \
        *(uint4*)((char*)&As[P][0] + wpos1) = rA1;                        \
        *(uint4*)((char*)&Bs[P][0] + wpos0) = rB0;                        \
        *(uint4*)((char*)&Bs[P][0] + wpos1) = rB1;                        \
        if ((T) + 2 < 16) LOADT(rA0, rA1, rB0, rB1, (T) + 2);             \
        asm volatile("s_waitcnt lgkmcnt(0)" ::: "memory");                \
        __builtin_amdgcn_s_barrier();                                     \
        const char* _rA = (const char*)&As[P][0];                         \
        const char* _rB = (const char*)&Bs[P][0];                         \
        bf16x8 av[8], bv[4];                                              \
        _Pragma("unroll")                                                 \
        for (int m = 0; m < 8; ++m) av[m] = *(const bf16x8*)(_rA + offA + m * 1024); \
        _Pragma("unroll")                                                 \
        for (int n = 0; n < 4; ++n) bv[n] = *(const bf16x8*)(_rB + offB + n * 1024); \
        _Pragma("unroll")                                                 \
        for (int m = 0; m < 8; ++m)                                       \
            _Pragma("unroll")                                             \
            for (int n = 0; n < 4; ++n)                                   \
                acc[m][n] = __builtin_amdgcn_mfma_f32_16x16x32_bf16(av[m], bv[n], acc[m][n], 0, 0, 0); \
    } while (0)

    // prologue: tiles 0,1 in regs (8 loads in flight)
    LOADT(eA0, eA1, eB0, eB1, 0);
    LOADT(oA0, oA1, oB0, oB1, 1);

#pragma unroll 1
    for (int tt = 0; tt < 16; tt += 2) {
        ITER(tt,     eA0, eA1, eB0, eB1, 0);
        ITER(tt + 1, oA0, oA1, oB0, oB1, 1);
    }
#undef ITER
#undef LOADT

    __syncthreads();                        // LDS free; reuse As for merge
    Top2 (*mrg)[4] = (Top2 (*)[4])&As[0][0];   // [256 rows][4 wave-cols] = 16 KB

    // epilogue: C row = (lane>>4)*4 + j (batch), col = lane&15 (code)
    const int rgrp = lane >> 4;
    const int cidx = lane & 15;
#pragma unroll
    for (int m = 0; m < 8; ++m) {
#pragma unroll
        for (int j = 0; j < 4; ++j) {
            float v1 = -INFINITY, v2 = -INFINITY;
            int   i1 = 0x7fffffff, i2 = 0x7fffffff;
#pragma unroll
            for (int n = 0; n < 4; ++n)
                top2_insert(acc[m][n][j], cb0 + wn * 64 + n * 16 + cidx, v1, i1, v2, i2);
            for (int off = 1; off < 16; off <<= 1) {
                float ov1 = __shfl_xor(v1, off); int oi1 = __shfl_xor(i1, off);
                float ov2 = __shfl_xor(v2, off); int oi2 = __shfl_xor(i2, off);
                if (ov1 > v1 || (ov1 == v1 && oi1 < i1)) {
                    float nv2; int ni2; pick_better(v1, i1, ov2, oi2, nv2, ni2);
                    v1 = ov1; i1 = oi1; v2 = nv2; i2 = ni2;
                } else {
                    float nv2; int ni2; pick_better(v2, i2, ov1, oi1, nv2, ni2);
                    v2 = nv2; i2 = ni2;
                }
            }
            if (cidx == 0) {
                Top2 p; p.v1 = v1; p.i1 = i1; p.v2 = v2; p.i2 = i2;
                mrg[wm * 128 + m * 16 + rgrp * 4 + j][wn] = p;
            }
        }
    }
    __syncthreads();
    if (tid < 256) {   // per 128-code half: same candidate structure as R2-R4
        Top2 x0 = mrg[tid][0], x1 = mrg[tid][1];
        float v1 = x0.v1, v2 = x0.v2; int i1 = x0.i1, i2 = x0.i2;
        top2_insert(x1.v1, x1.i1, v1, i1, v2, i2);
        top2_insert(x1.v2, x1.i2, v1, i1, v2, i2);
        Top2 p; p.v1 = v1; p.i1 = i1; p.v2 = v2; p.i2 = i2;
        part[(size_t)(rb0 + tid) * NTB + col_tile * 2] = p;
        Top2 y0 = mrg[tid][2], y1 = mrg[tid][3];
        v1 = y0.v1; v2 = y0.v2; i1 = y0.i1; i2 = y0.i2;
        top2_insert(y1.v1, y1.i1, v1, i1, v2, i2);
        top2_insert(y1.v2, y1.i2, v1, i1, v2, i2);
        p.v1 = v1; p.i1 = i1; p.v2 = v2; p.i2 = i2;
        part[(size_t)(rb0 + tid) * NTB + col_tile * 2 + 1] = p;
    }
}

// Per row: exact fp32 re-dot of candidates within MARGIN of the bf16 max, argmax,
// residual update (fp32 chain via out_stack + bf16 mirror), per-block loss partial
// (no atomics), usage; layer NL-1 also writes quantized = x - r.
__global__ __launch_bounds__(256)
void k_refine(const Top2* __restrict__ part, const float* __restrict__ CB,
              const float* __restrict__ prevBase, size_t prevStride,
              const float* __restrict__ X, float* __restrict__ out_q,
              float* __restrict__ stack, u16* __restrict__ residb,
              float* __restrict__ out_usage, float* __restrict__ pl,
              int layer)
{
    __shared__ float row[DD];
    __shared__ float candV[64];
    __shared__ int   candI[64];
    __shared__ float s_thr;
    __shared__ float wbv[4];
    __shared__ int   wbi[4];
    __shared__ int   s_best;
    __shared__ float red[256];

    const int b = blockIdx.x;
    const int tid = threadIdx.x;
    const float* pr = prevBase + (size_t)b * prevStride;
    row[tid]       = pr[tid];
    row[tid + 256] = pr[tid + 256];
    if (tid < 64) {
        Top2 p = part[(size_t)b * NTB + (tid >> 1)];
        candV[tid] = (tid & 1) ? p.v2 : p.v1;
        candI[tid] = (tid & 1) ? p.i2 : p.i1;
    }
    __syncthreads();
    if (tid < 64) {
        float v = candV[tid];
        for (int off = 1; off < 64; off <<= 1) v = fmaxf(v, __shfl_xor(v, off));
        if (tid == 0) s_thr = v - MARGIN;
    }
    __syncthreads();
    const float thr = s_thr;

    const int wave = tid >> 6;
    const int lane = tid & 63;
    float bestV = -INFINITY;
    int   bestI = 0x7fffffff;
    for (int s = 0; s < 16; ++s) {
        const int c = wave * 16 + s;
        if (candV[c] < thr) continue;          // wave-uniform skip
        const int ci = candI[c];
        const float* cr = CB + (size_t)ci * DD;
        float p = 0.f;
#pragma unroll
        for (int q = 0; q < 8; ++q)
            p = fmaf(row[lane * 8 + q], cr[lane * 8 + q], p);
        for (int off = 32; off >= 1; off >>= 1) p += __shfl_xor(p, off);
        if (p > bestV || (p == bestV && ci < bestI)) { bestV = p; bestI = ci; }
    }
    if (lane == 0) { wbv[wave] = bestV; wbi[wave] = bestI; }
    __syncthreads();
    if (tid == 0) {
        float bv = wbv[0]; int bi = wbi[0];
        for (int k = 1; k < 4; ++k)
            if (wbv[k] > bv || (wbv[k] == bv && wbi[k] < bi)) { bv = wbv[k]; bi = wbi[k]; }
        s_best = bi;
        out_usage[layer * KC + bi] = 1.0f;
    }
    __syncthreads();
    const int bi = s_best;

    const float* cr = CB + (size_t)bi * DD;
    const float rn0 = row[tid]       - cr[tid];
    const float rn1 = row[tid + 256] - cr[tid + 256];
    float* sp = stack + ((size_t)b * NL + layer) * DD;   // base odd-aligned -> scalar
    sp[tid]       = rn0;
    sp[tid + 256] = rn1;
    residb[(size_t)b * DD + tid]       = f2bf(rn0);
    residb[(size_t)b * DD + tid + 256] = f2bf(rn1);
    if (layer == NL - 1) {
        out_q[(size_t)b * DD + tid]       = X[(size_t)b * DD + tid]       - rn0;
        out_q[(size_t)b * DD + tid + 256] = X[(size_t)b * DD + tid + 256] - rn1;
    }
    red[tid] = rn0 * rn0 + rn1 * rn1;
    __syncthreads();
    for (int st = 128; st > 0; st >>= 1) {
        if (tid < st) red[tid] += red[tid + st];
        __syncthreads();
    }
    if (tid == 0) pl[(size_t)layer * NB + b] = red[0];
}

__global__ __launch_bounds__(256)
void k_cbsq(const float* __restrict__ cb, double* __restrict__ cq)
{
    __shared__ double red[256];
    const size_t n = (size_t)NL * KC * DD;
    double s = 0.0;
    for (size_t i = (size_t)blockIdx.x * blockDim.x + threadIdx.x; i < n;
         i += (size_t)gridDim.x * blockDim.x) {
        const float v = cb[i];
        s += (double)v * (double)v;
    }
    red[threadIdx.x] = s;
    __syncthreads();
    for (int st = 128; st > 0; st >>= 1) {
        if (threadIdx.x < st) red[threadIdx.x] += red[threadIdx.x + st];
        __syncthreads();
    }
    if (threadIdx.x == 0) cq[blockIdx.x] = red[0];
}

__global__ __launch_bounds__(256)
void k_finalize(const float* __restrict__ pl, const double* __restrict__ cq,
                float* __restrict__ out_loss)
{
    __shared__ double red[256];
    const int tid = threadIdx.x;
    double s = 0.0;
    for (int i = tid; i < NL * NB; i += 256) s += (double)pl[i];
    double s2 = 0.0;
    for (int i = tid; i < 1024; i += 256) s2 += cq[i];
    red[tid] = s / ((double)NB * DD) + 0.01 * (s2 / ((double)NL * KC));
    __syncthreads();
    for (int st = 128; st > 0; st >>= 1) {
        if (tid < st) red[tid] += red[tid + st];
        __syncthreads();
    }
    if (tid == 0) out_loss[0] = (float)(red[0] / (double)DD);
}

extern "C" void kernel_launch(void* const* d_in, const int* in_sizes, int n_in,
                              void* d_out, int out_size, void* d_ws, size_t ws_size,
                              hipStream_t stream)
{
    (void)in_sizes; (void)n_in; (void)out_size; (void)ws_size;
    const float* x  = (const float*)d_in[0];
    // d_in[1] = temperature: positive scale, argmax-invariant, soft path cancels -> unused
    const float* cb = (const float*)d_in[2];

    float* out       = (float*)d_out;
    float* out_q     = out;                                   // [NB, DD]
    float* out_loss  = out + (size_t)NB * DD;                 // [1]
    float* out_stack = out_loss + 1;                          // [NB, NL, DD] (fp32 residual chain)
    float* out_usage = out_stack + (size_t)NB * NL * DD;      // [NL, KC]

    char* ws = (char*)d_ws;
    Top2*  part   = (Top2*)ws;                                // 4 MB
    u16*   residb = (u16*)(ws + ((size_t)4 << 20));           // 8 MB bf16 residual mirror
    u16*   cbb    = (u16*)(ws + ((size_t)12 << 20));          // 4 MB bf16 codebook (per layer)
    float* pl     = (float*)(ws + ((size_t)16 << 20));        // NL*NB loss partials (128 KB)
    double* cq    = (double*)(ws + ((size_t)16 << 20) + 131072 + 256); // 1024 cbsq partials

    hipMemsetAsync(out_usage, 0, (size_t)NL * KC * sizeof(float), stream);

    k_cvt_bf16<<<(NB * DD / 4 + 255) / 256, 256, 0, stream>>>(x, residb, NB * DD / 4);
    k_cbsq<<<1024, 256, 0, stream>>>(cb, cq);

    for (int l = 0; l < NL; ++l) {
        const float* cbl = cb + (size_t)l * KC * DD;
        k_cvt_bf16<<<(KC * DD / 4 + 255) / 256, 256, 0, stream>>>(cbl, cbb, KC * DD / 4);
        k_simtop2<<<512, 512, 0, stream>>>(residb, cbb, part);
        const float* prevBase = (l == 0) ? x : (out_stack + (size_t)(l - 1) * DD);
        const size_t prevStride = (l == 0) ? (size_t)DD : (size_t)NL * DD;
        k_refine<<<NB, 256, 0, stream>>>(part, cbl, prevBase, prevStride, x, out_q,
                                         out_stack, residb, out_usage, pl, l);
    }
    k_finalize<<<1, 256, 0, stream>>>(pl, cq, out_loss);
}